// Round 6
// baseline (10544.989 us; speedup 1.0000x reference)
//
#include <hip/hip_runtime.h>
#include <cstdint>

typedef unsigned short u16;
typedef unsigned int u32;
typedef float f32x4 __attribute__((ext_vector_type(4)));
typedef short s16x8 __attribute__((ext_vector_type(8)));

#define DEV static __device__ __forceinline__

#define TT 128
#define BB 256
#define OBSD 128
#define HHD 512
#define AD 18
#define GGD 2048
#define MMD 32768

DEV u16 f2bf(float f) {
  u32 u = __builtin_bit_cast(u32, f);
  u += 0x7fffu + ((u >> 16) & 1u);
  return (u16)(u >> 16);
}
DEV float bf2f(u16 h) { return __builtin_bit_cast(float, ((u32)h) << 16); }

DEV f32x4 mfma16x16x32(s16x8 a, s16x8 b, f32x4 c) {
  // D = A*B + C, C/D layout: col=lane&15, row=(lane>>4)*4+reg  [m89/m91]
  asm("v_mfma_f32_16x16x32_bf16 %0, %1, %2, %0" : "+v"(c) : "v"(a), "v"(b));
  return c;
}
// Inline-asm MFMA: hazard recognizer can't see it -> manual wait states (proven R3).
DEV void fence_mfma_read(f32x4& x) { asm volatile("s_nop 7" : "+v"(x)); }
DEV void fence_mfma_srcc(f32x4& x) { asm volatile("s_nop 1" : "+v"(x)); }

// async global->LDS, 16B/lane; LDS dest is wave-uniform base + lane*16 (m97/m104)
typedef __attribute__((address_space(3))) char lds_char;
typedef __attribute__((address_space(1))) const char gl_char;
DEV void gload16(const char* g, char* l) {
  __builtin_amdgcn_global_load_lds((const gl_char*)g, (lds_char*)l, 16, 0, 0);
}

DEV float sigm(float x) { return 1.f / (1.f + __expf(-x)); }
DEV float tanh_fast(float x) {
  float t = __expf(-2.f * fabsf(x));
  float r = (1.f - t) / (1.f + t);
  return copysignf(r, x);
}

// ---------------- workspace layout (bytes), total ~218MB ----------------
constexpr size_t OFF_CBUF  = 0;          // 524288  (unused by scan now; prep kept identical)
constexpr size_t OFF_HRING = 524288;     // 524288  (h_init = h0*keep0, [256][512] bf16)
constexpr size_t OFF_TW0T  = 1048576;    // 131072
constexpr size_t OFF_TW1T  = 1179648;    // 524288
constexpr size_t OFF_AW0T  = 1703936;    // 524288
constexpr size_t OFF_VW0T  = 2228224;    // 524288 (contiguous with AW0T)
constexpr size_t OFF_AW1T  = 2752512;    // 18432
constexpr size_t OFF_VW1T  = 2770944;    // 1024
constexpr size_t OFF_WIH   = 2772992;    // 2097152
constexpr size_t OFF_WHH   = 4870144;    // 2097152
constexpr size_t OFF_BSUM  = 6967296;    // 8192
constexpr size_t OFF_WRC   = 6975488;    // 8192
constexpr size_t OFF_WEMB  = 6983680;    // 147456
constexpr size_t OFF_BCAT  = 7131136;    // 4096
constexpr size_t OFF_OBF   = 8388608;    // 8388608
constexpr size_t OFF_BUF1  = 16777216;   // 33554432  (h1, later hs)
constexpr size_t OFF_BUF2  = 50331648;   // 33554432  (hid)
constexpr size_t OFF_BUF3  = 83886080;   // 134217728 (xg, later hv [32768][1024])

// ---------------- prep: convert/transpose weights, convert o, init h_init & c ----------------
__global__ __launch_bounds__(256) void prep(
    const float* __restrict__ o, const float* __restrict__ tW0,
    const float* __restrict__ tW1, const float* __restrict__ aW0,
    const float* __restrict__ vW0, const float* __restrict__ aW1,
    const float* __restrict__ vW1, const float* __restrict__ Wih,
    const float* __restrict__ WhhF, const float* __restrict__ bih,
    const float* __restrict__ bhh, const float* __restrict__ h0,
    const float* __restrict__ c0, const float* __restrict__ done,
    const float* __restrict__ ab0, const float* __restrict__ vb0,
    u16* __restrict__ o_bf, u16* __restrict__ tW0T, u16* __restrict__ tW1T,
    u16* __restrict__ aW0T, u16* __restrict__ vW0T, u16* __restrict__ aW1T,
    u16* __restrict__ vW1T, u16* __restrict__ WihB, u16* __restrict__ WhhB,
    float* __restrict__ bsum, float* __restrict__ wrc, float* __restrict__ wemb,
    float* __restrict__ bcat, u16* __restrict__ hring, float* __restrict__ c_buf)
{
  const int total = 4309504;
  for (int id = blockIdx.x * 256 + threadIdx.x; id < total; id += gridDim.x * 256) {
    int i = id;
    if (i < 1048576) {  // o -> bf16, x4
      float4 v = ((const float4*)o)[i];
      u16* dst = o_bf + (size_t)i * 4;
      dst[0] = f2bf(v.x); dst[1] = f2bf(v.y); dst[2] = f2bf(v.z); dst[3] = f2bf(v.w);
      continue;
    }
    i -= 1048576;
    if (i < 65536)  { int n = i >> 7, k = i & 127; tW0T[i] = f2bf(tW0[k * 512 + n]); continue; }
    i -= 65536;
    if (i < 262144) { int n = i >> 9, k = i & 511; tW1T[i] = f2bf(tW1[k * 512 + n]); continue; }
    i -= 262144;
    if (i < 262144) { int n = i >> 9, k = i & 511; aW0T[i] = f2bf(aW0[k * 512 + n]); continue; }
    i -= 262144;
    if (i < 262144) { int n = i >> 9, k = i & 511; vW0T[i] = f2bf(vW0[k * 512 + n]); continue; }
    i -= 262144;
    if (i < 9216)   { int n = i >> 9, k = i & 511; aW1T[i] = f2bf(aW1[k * 18 + n]); continue; }
    i -= 9216;
    if (i < 512)    { vW1T[i] = f2bf(vW1[i]); continue; }
    i -= 512;
    if (i < 1048576){ int g = i >> 9, k = i & 511; WihB[i] = f2bf(Wih[g * 531 + k]); continue; }
    i -= 1048576;
    if (i < 1048576){ WhhB[i] = f2bf(WhhF[i]); continue; }
    i -= 1048576;
    if (i < 2048)   { bsum[i] = bih[i] + bhh[i]; wrc[i] = Wih[i * 531 + 512]; continue; }
    i -= 2048;
    if (i < 36864)  { int j = i >> 11, g = i & 2047; wemb[i] = Wih[g * 531 + 513 + j]; continue; }
    i -= 36864;
    if (i < 1024)   { bcat[i] = (i < 512) ? ab0[i] : vb0[i - 512]; continue; }
    i -= 1024;
    if (i < 131072) { int b = i >> 9; hring[i] = f2bf(h0[i] * (1.f - done[b])); continue; }
    i -= 131072;
    { c_buf[i] = c0[i]; }
  }
}

// ---------------- bf16 MFMA GEMM: C[M][N] = A[M][K] * Bt[N][K]^T + epilogue ----------------
// Staging via global_load_lds w=16: linear LDS dest, inverse-swizzled global src (rule #21).
template<int MODE>
__global__ __launch_bounds__(256) void gemm_bt(
    const u16* __restrict__ A, const u16* __restrict__ Bt, u16* __restrict__ C,
    int Mdim, int Ndim, int Kdim,
    const float* __restrict__ bias,
    const float* __restrict__ wrc, const float* __restrict__ wemb,
    const float* __restrict__ rin, const int* __restrict__ ain)
{
  __shared__ __align__(16) char smem[32768];  // A tile 16KB | B tile 16KB
  const int tid = threadIdx.x;
  const int nTn = Ndim >> 7;
  int wg = blockIdx.x;
  {  // XCD-aware swizzle (grid % 8 == 0 for all our launches)
    const int per = gridDim.x >> 3;
    wg = (wg & 7) * per + (wg >> 3);
  }
  const int tm = wg / nTn, tn = wg % nTn;
  const int wid = tid >> 6, lane = tid & 63;
  const int wr = wid >> 1, wc = wid & 1;
  const int l15 = lane & 15, l4 = lane >> 4;

  f32x4 acc[4][4];
#pragma unroll
  for (int i = 0; i < 4; ++i)
#pragma unroll
    for (int j = 0; j < 4; ++j) acc[i][j] = f32x4{0.f, 0.f, 0.f, 0.f};

  const int srow = lane >> 3;               // row within 8-row stripe == row&7
  const int scolb = ((lane & 7) * 16) ^ (srow << 4);  // inverse-swizzled byte col
  const size_t kd2 = (size_t)Kdim * 2;
  const char* Abase = (const char*)(A + (size_t)tm * 128 * Kdim);
  const char* Bbase = (const char*)(Bt + (size_t)tn * 128 * Kdim);
  const char* ga[4]; const char* gb[4]; char* la[4]; char* lb[4];
#pragma unroll
  for (int j = 0; j < 4; ++j) {
    const int row = wid * 32 + j * 8 + srow;
    ga[j] = Abase + (size_t)row * kd2 + scolb;
    gb[j] = Bbase + (size_t)row * kd2 + scolb;
    la[j] = smem + wid * 4096 + j * 1024;
    lb[j] = smem + 16384 + wid * 4096 + j * 1024;
  }

  for (int k0 = 0; k0 < Kdim; k0 += 64) {
    const size_t kb = (size_t)k0 * 2;
#pragma unroll
    for (int j = 0; j < 4; ++j) {
      gload16(ga[j] + kb, la[j]);
      gload16(gb[j] + kb, lb[j]);
    }
    __syncthreads();  // drains vmcnt -> LDS tiles complete
#pragma unroll
    for (int kk = 0; kk < 2; ++kk) {
      s16x8 af[4], bfr[4];
#pragma unroll
      for (int i = 0; i < 4; ++i) {
        int ar = wr * 64 + i * 16 + l15;
        af[i] = *(const s16x8*)(smem + ((ar * 128 + kk * 64 + l4 * 16) ^ ((ar & 7) << 4)));
        int br = wc * 64 + i * 16 + l15;
        bfr[i] = *(const s16x8*)(smem + 16384 + ((br * 128 + kk * 64 + l4 * 16) ^ ((br & 7) << 4)));
      }
#pragma unroll
      for (int i = 0; i < 4; ++i)
#pragma unroll
        for (int j = 0; j < 4; ++j)
          acc[i][j] = mfma16x16x32(af[i], bfr[j], acc[i][j]);
    }
    __syncthreads();
  }

#pragma unroll
  for (int i = 0; i < 4; ++i)
#pragma unroll
    for (int j = 0; j < 4; ++j) fence_mfma_read(acc[i][j]);

#pragma unroll
  for (int i = 0; i < 4; ++i) {
    const int rowb = tm * 128 + wr * 64 + i * 16 + l4 * 4;
    float rv[4]; int av[4];
    if (MODE == 1) {
#pragma unroll
      for (int r = 0; r < 4; ++r) { rv[r] = rin[rowb + r]; av[r] = ain[rowb + r]; }
    }
#pragma unroll
    for (int j = 0; j < 4; ++j) {
      const int col = tn * 128 + wc * 64 + j * 16 + l15;
      const float bs = bias[col];
      if (MODE == 0) {
#pragma unroll
        for (int r = 0; r < 4; ++r) {
          float x = acc[i][j][r] + bs;
          x = fmaxf(x, 0.f);
          C[(size_t)(rowb + r) * Ndim + col] = f2bf(x);
        }
      } else {
        const float wcv = wrc[col];
#pragma unroll
        for (int r = 0; r < 4; ++r) {
          float x = acc[i][j][r] + bs + rv[r] * wcv + wemb[av[r] * GGD + col];
          C[(size_t)(rowb + r) * Ndim + col] = f2bf(x);
        }
      }
    }
  }
}

// ---------------- full LSTM scan, ONE kernel ----------------
// Batch rows are independent across the whole scan -> 16 blocks x 16 rows, zero
// cross-block sync. Per block: h double-buffered in LDS (2x16KB, XOR-swizzled),
// c in registers, W_hh streamed from L2 (2MB, XCD-resident), xg via 64-reg
// scalar prefetch (one step ahead). 8 waves x 64 units each: every wave holds
// i,f,g,o for its units -> epilogue is lane-local.
__global__ __launch_bounds__(512, 2) void lstm_scan(
    const u16* __restrict__ xg, const u16* __restrict__ WhhB,
    const float* __restrict__ done, const float* __restrict__ c0,
    const u16* __restrict__ h_init, u16* __restrict__ hs,
    float* __restrict__ hT, float* __restrict__ cT)
{
  __shared__ __align__(16) char hsm[2][16384];
  const int tid = threadIdx.x;
  const int b0 = blockIdx.x * 16;
  const int wid = tid >> 6, lane = tid & 63;
  const int l15 = lane & 15, l4 = lane >> 4;
  const int ubase = wid * 64;

  // stage h_init (pre-scaled by keep0) into h_lds[0], swizzled
  for (int i = tid; i < 1024; i += 512) {
    int row = i >> 6;
    int cb = (i & 63) * 16;
    uint4 v = *(const uint4*)((const char*)(h_init + (size_t)(b0 + row) * HHD) + cb);
    *(uint4*)(hsm[0] + ((row * 1024 + cb) ^ ((row & 7) << 4))) = v;
  }

  // c state: c_[j][r] for (row = l4*4+r, unit = ubase + j*16 + l15)
  float c_[4][4];
#pragma unroll
  for (int j = 0; j < 4; ++j)
#pragma unroll
    for (int r = 0; r < 4; ++r)
      c_[j][r] = c0[(size_t)(b0 + l4 * 4 + r) * HHD + ubase + j * 16 + l15];

  // xg prefetch regs for t=0: ct = g*4+j
  u16 xpf[64];
#pragma unroll
  for (int r = 0; r < 4; ++r) {
    const u16* base = xg + (size_t)(b0 + l4 * 4 + r) * GGD + ubase + l15;
#pragma unroll
    for (int g = 0; g < 4; ++g)
#pragma unroll
      for (int j = 0; j < 4; ++j)
        xpf[(g * 4 + j) * 4 + r] = base[g * 512 + j * 16];
  }
  float keepc[4];
#pragma unroll
  for (int r = 0; r < 4; ++r)
    keepc[r] = 1.f - done[b0 + l4 * 4 + r];

  __syncthreads();

  int cur = 0;
  for (int t = 0; t < TT; ++t) {
    // acc init = xg (SrcC), then fence VALU->MFMA
    f32x4 acc[16];
#pragma unroll
    for (int ct = 0; ct < 16; ++ct) {
#pragma unroll
      for (int r = 0; r < 4; ++r) acc[ct][r] = bf2f(xpf[ct * 4 + r]);
    }
#pragma unroll
    for (int ct = 0; ct < 16; ++ct) fence_mfma_srcc(acc[ct]);

    // prefetch next step's xg + keep (hidden under MFMAs)
    const int tn = (t + 1 < TT) ? t + 1 : t;
#pragma unroll
    for (int r = 0; r < 4; ++r) {
      const u16* base = xg + ((size_t)tn * BB + b0 + l4 * 4 + r) * GGD + ubase + l15;
#pragma unroll
      for (int g = 0; g < 4; ++g)
#pragma unroll
        for (int j = 0; j < 4; ++j)
          xpf[(g * 4 + j) * 4 + r] = base[g * 512 + j * 16];
    }
    float keepn[4];
#pragma unroll
    for (int r = 0; r < 4; ++r)
      keepn[r] = (t + 1 < TT) ? (1.f - done[(size_t)(t + 1) * BB + b0 + l4 * 4 + r]) : 1.f;

    // 256 MFMAs: A from h_lds[cur] (16 ds_read_b128), B from W_hh (L2)
    const char* hbase = hsm[cur];
#pragma unroll
    for (int ks = 0; ks < 16; ++ks) {
      s16x8 a = *(const s16x8*)(hbase + ((l15 * 1024 + ks * 64 + l4 * 16) ^ ((l15 & 7) << 4)));
#pragma unroll
      for (int ct = 0; ct < 16; ++ct) {
        const int g = ct >> 2, j = ct & 3;
        s16x8 b = *(const s16x8*)(WhhB +
            (size_t)(g * 512 + ubase + j * 16 + l15) * HHD + ks * 32 + l4 * 8);
        acc[ct] = mfma16x16x32(a, b, acc[ct]);
      }
    }
#pragma unroll
    for (int ct = 0; ct < 16; ++ct) fence_mfma_read(acc[ct]);

    // epilogue: lane-local gates -> c,h; h*keep(t+1) -> h_lds[next]; h -> hs
    char* hnext = hsm[cur ^ 1];
#pragma unroll
    for (int j = 0; j < 4; ++j) {
#pragma unroll
      for (int r = 0; r < 4; ++r) {
        const int row = l4 * 4 + r;
        const int u = ubase + j * 16 + l15;
        float iv = sigm(acc[0 + j][r]);
        float fv = sigm(acc[4 + j][r]);
        float gv = tanh_fast(acc[8 + j][r]);
        float ov = sigm(acc[12 + j][r]);
        float c = fv * (c_[j][r] * keepc[r]) + iv * gv;
        float h = ov * tanh_fast(c);
        c_[j][r] = c;
        hs[((size_t)t * BB + b0 + row) * HHD + u] = f2bf(h);
        if (t < TT - 1) {
          *(u16*)(hnext + ((row * 1024 + u * 2) ^ ((row & 7) << 4))) = f2bf(h * keepn[r]);
        } else {
          hT[(size_t)(b0 + row) * HHD + u] = h;
          cT[(size_t)(b0 + row) * HHD + u] = c;
        }
      }
    }
#pragma unroll
    for (int r = 0; r < 4; ++r) keepc[r] = keepn[r];

    __syncthreads();
    cur ^= 1;
  }
}

// ---------------- final heads: adv(18) + val + dueling combine ----------------
__global__ __launch_bounds__(256) void head_final(
    const u16* __restrict__ hv, const u16* __restrict__ aW1T,
    const u16* __restrict__ vW1T, const float* __restrict__ ab1,
    const float* __restrict__ vb1, float* __restrict__ q)
{
  __shared__ __align__(16) u16 wa[AD * HHD];
  __shared__ __align__(16) u16 wv[HHD];
  const int tid = threadIdx.x;
  for (int i = tid; i < AD * HHD / 8; i += 256) ((uint4*)wa)[i] = ((const uint4*)aW1T)[i];
  for (int i = tid; i < HHD / 8; i += 256) ((uint4*)wv)[i] = ((const uint4*)vW1T)[i];
  __syncthreads();
  const int wid = tid >> 6, lane = tid & 63;
  for (int row = blockIdx.x * 4 + wid; row < MMD; row += gridDim.x * 4) {
    uint4 va = *(const uint4*)(hv + (size_t)row * 1024 + lane * 8);
    uint4 vv = *(const uint4*)(hv + (size_t)row * 1024 + 512 + lane * 8);
    const u16* pa = (const u16*)&va;
    const u16* pv = (const u16*)&vv;
    float af[8], vf[8];
#pragma unroll
    for (int j = 0; j < 8; ++j) { af[j] = bf2f(pa[j]); vf[j] = bf2f(pv[j]); }
    float accs[19];
#pragma unroll
    for (int n = 0; n < 19; ++n) accs[n] = 0.f;
#pragma unroll
    for (int n = 0; n < AD; ++n) {
      const u16* w = wa + n * HHD + lane * 8;
#pragma unroll
      for (int j = 0; j < 8; ++j) accs[n] += af[j] * bf2f(w[j]);
    }
    {
      const u16* w = wv + lane * 8;
#pragma unroll
      for (int j = 0; j < 8; ++j) accs[18] += vf[j] * bf2f(w[j]);
    }
#pragma unroll
    for (int n = 0; n < 19; ++n) {
#pragma unroll
      for (int off = 32; off > 0; off >>= 1)
        accs[n] += __shfl_xor(accs[n], off, 64);
    }
    if (lane == 0) {
      float s = 0.f;
      float advv[AD];
#pragma unroll
      for (int n = 0; n < AD; ++n) { advv[n] = accs[n] + ab1[n]; s += advv[n]; }
      float val = accs[18] + vb1[0];
      float mean = s * (1.f / 18.f);
#pragma unroll
      for (int n = 0; n < AD; ++n) q[(size_t)row * AD + n] = val + advv[n] - mean;
    }
  }
}

// ---------------- launch ----------------
extern "C" void kernel_launch(void* const* d_in, const int* in_sizes, int n_in,
                              void* d_out, int out_size, void* d_ws, size_t ws_size,
                              hipStream_t stream) {
  const float* o    = (const float*)d_in[0];
  const int*   a    = (const int*)d_in[1];
  const float* r    = (const float*)d_in[2];
  const float* done = (const float*)d_in[3];
  const float* h0   = (const float*)d_in[4];
  const float* c0   = (const float*)d_in[5];
  const float* tW0  = (const float*)d_in[6];
  const float* tb0  = (const float*)d_in[7];
  const float* tW1  = (const float*)d_in[8];
  const float* tb1  = (const float*)d_in[9];
  const float* Wih  = (const float*)d_in[10];
  const float* Whh  = (const float*)d_in[11];
  const float* bih  = (const float*)d_in[12];
  const float* bhh  = (const float*)d_in[13];
  const float* aW0  = (const float*)d_in[14];
  const float* ab0  = (const float*)d_in[15];
  const float* aW1  = (const float*)d_in[16];
  const float* ab1  = (const float*)d_in[17];
  const float* vW0  = (const float*)d_in[18];
  const float* vb0  = (const float*)d_in[19];
  const float* vW1  = (const float*)d_in[20];
  const float* vb1  = (const float*)d_in[21];
  (void)in_sizes; (void)n_in; (void)ws_size;

  char* ws = (char*)d_ws;
  float* c_buf = (float*)(ws + OFF_CBUF);
  u16* hring  = (u16*)(ws + OFF_HRING);   // h_init
  u16* tW0T   = (u16*)(ws + OFF_TW0T);
  u16* tW1T   = (u16*)(ws + OFF_TW1T);
  u16* aW0T   = (u16*)(ws + OFF_AW0T);
  u16* vW0T   = (u16*)(ws + OFF_VW0T);
  u16* aW1T   = (u16*)(ws + OFF_AW1T);
  u16* vW1T   = (u16*)(ws + OFF_VW1T);
  u16* WihB   = (u16*)(ws + OFF_WIH);
  u16* WhhB   = (u16*)(ws + OFF_WHH);
  float* bsum = (float*)(ws + OFF_BSUM);
  float* wrc  = (float*)(ws + OFF_WRC);
  float* wemb = (float*)(ws + OFF_WEMB);
  float* bcat = (float*)(ws + OFF_BCAT);
  u16* o_bf   = (u16*)(ws + OFF_OBF);
  u16* buf1   = (u16*)(ws + OFF_BUF1);  // h1, later hs
  u16* buf2   = (u16*)(ws + OFF_BUF2);  // hid
  u16* buf3   = (u16*)(ws + OFF_BUF3);  // xg, later hv

  float* qout = (float*)d_out;
  float* hT   = qout + (size_t)TT * BB * AD;
  float* cT   = hT + (size_t)BB * HHD;

  prep<<<2048, 256, 0, stream>>>(o, tW0, tW1, aW0, vW0, aW1, vW1, Wih, Whh,
                                 bih, bhh, h0, c0, done, ab0, vb0,
                                 o_bf, tW0T, tW1T, aW0T, vW0T, aW1T, vW1T,
                                 WihB, WhhB, bsum, wrc, wemb, bcat, hring, c_buf);
  gemm_bt<0><<<1024, 256, 0, stream>>>(o_bf, tW0T, buf1, MMD, 512, 128, tb0,
                                       nullptr, nullptr, nullptr, nullptr);
  gemm_bt<0><<<1024, 256, 0, stream>>>(buf1, tW1T, buf2, MMD, 512, 512, tb1,
                                       nullptr, nullptr, nullptr, nullptr);
  gemm_bt<1><<<4096, 256, 0, stream>>>(buf2, WihB, buf3, MMD, 2048, 512, bsum,
                                       wrc, wemb, r, a);
  lstm_scan<<<16, 512, 0, stream>>>(buf3, WhhB, done, c0, hring,
                                    buf1 /*hs*/, hT, cT);
  gemm_bt<0><<<2048, 256, 0, stream>>>(buf1 /*hs*/, aW0T, buf3 /*hv*/, MMD, 1024, 512, bcat,
                                       nullptr, nullptr, nullptr, nullptr);
  head_final<<<2048, 256, 0, stream>>>(buf3, aW1T, vW1T, ab1, vb1, qout);
}

// Round 7
// 1692.594 us; speedup vs baseline: 6.2301x; 6.2301x over previous
//
#include <hip/hip_runtime.h>
#include <cstdint>

typedef unsigned short u16;
typedef unsigned int u32;
typedef float f32x4 __attribute__((ext_vector_type(4)));
typedef short s16x8 __attribute__((ext_vector_type(8)));

#define DEV static __device__ __forceinline__

#define TT 128
#define BB 256
#define OBSD 128
#define HHD 512
#define AD 18
#define GGD 2048
#define MMD 32768

DEV u16 f2bf(float f) {
  u32 u = __builtin_bit_cast(u32, f);
  u += 0x7fffu + ((u >> 16) & 1u);
  return (u16)(u >> 16);
}
DEV float bf2f(u16 h) { return __builtin_bit_cast(float, ((u32)h) << 16); }

DEV f32x4 mfma16x16x32(s16x8 a, s16x8 b, f32x4 c) {
  // D = A*B + C, C/D layout: col=lane&15, row=(lane>>4)*4+reg  [m89/m91]
  asm("v_mfma_f32_16x16x32_bf16 %0, %1, %2, %0" : "+v"(c) : "v"(a), "v"(b));
  return c;
}
// Inline-asm MFMA: hazard recognizer can't see it -> manual wait states (proven R3).
DEV void fence_mfma_read(f32x4& x) { asm volatile("s_nop 7" : "+v"(x)); }
DEV void fence_mfma_srcc(f32x4& x) { asm volatile("s_nop 1" : "+v"(x)); }

// async global->LDS, 16B/lane; LDS dest is wave-uniform base + lane*16 (m97/m104)
typedef __attribute__((address_space(3))) char lds_char;
typedef __attribute__((address_space(1))) const char gl_char;
DEV void gload16(const char* g, char* l) {
  __builtin_amdgcn_global_load_lds((const gl_char*)g, (lds_char*)l, 16, 0, 0);
}

DEV float sigm(float x) { return 1.f / (1.f + __expf(-x)); }
DEV float tanh_fast(float x) {
  float t = __expf(-2.f * fabsf(x));
  float r = (1.f - t) / (1.f + t);
  return copysignf(r, x);
}

// ---------------- workspace layout (bytes), total ~218MB ----------------
constexpr size_t OFF_FLAGS = 0;          // 65536 (4bg x 128t x 32ug x 4B)
constexpr size_t OFF_HRING = 524288;     // 524288  (2 x [256][512] bf16)
constexpr size_t OFF_TW0T  = 1048576;    // 131072
constexpr size_t OFF_TW1T  = 1179648;    // 524288
constexpr size_t OFF_AW0T  = 1703936;    // 524288
constexpr size_t OFF_VW0T  = 2228224;    // 524288 (contiguous with AW0T)
constexpr size_t OFF_AW1T  = 2752512;    // 18432
constexpr size_t OFF_VW1T  = 2770944;    // 1024
constexpr size_t OFF_WIH   = 2772992;    // 2097152
constexpr size_t OFF_WHH   = 4870144;    // 2097152
constexpr size_t OFF_BSUM  = 6967296;    // 8192
constexpr size_t OFF_WRC   = 6975488;    // 8192
constexpr size_t OFF_WEMB  = 6983680;    // 147456
constexpr size_t OFF_BCAT  = 7131136;    // 4096
constexpr size_t OFF_OBF   = 8388608;    // 8388608
constexpr size_t OFF_BUF1  = 16777216;   // 33554432  (h1, later hs)
constexpr size_t OFF_BUF2  = 50331648;   // 33554432  (hid)
constexpr size_t OFF_BUF3  = 83886080;   // 134217728 (xg, later hv [32768][1024])

// ---------------- prep: convert/transpose weights, convert o, init h-ring ----------------
__global__ __launch_bounds__(256) void prep(
    const float* __restrict__ o, const float* __restrict__ tW0,
    const float* __restrict__ tW1, const float* __restrict__ aW0,
    const float* __restrict__ vW0, const float* __restrict__ aW1,
    const float* __restrict__ vW1, const float* __restrict__ Wih,
    const float* __restrict__ WhhF, const float* __restrict__ bih,
    const float* __restrict__ bhh, const float* __restrict__ h0,
    const float* __restrict__ done, const float* __restrict__ ab0,
    const float* __restrict__ vb0,
    u16* __restrict__ o_bf, u16* __restrict__ tW0T, u16* __restrict__ tW1T,
    u16* __restrict__ aW0T, u16* __restrict__ vW0T, u16* __restrict__ aW1T,
    u16* __restrict__ vW1T, u16* __restrict__ WihB, u16* __restrict__ WhhB,
    float* __restrict__ bsum, float* __restrict__ wrc, float* __restrict__ wemb,
    float* __restrict__ bcat, u16* __restrict__ hring)
{
  const int total = 4178432;
  for (int id = blockIdx.x * 256 + threadIdx.x; id < total; id += gridDim.x * 256) {
    int i = id;
    if (i < 1048576) {  // o -> bf16, x4
      float4 v = ((const float4*)o)[i];
      u16* dst = o_bf + (size_t)i * 4;
      dst[0] = f2bf(v.x); dst[1] = f2bf(v.y); dst[2] = f2bf(v.z); dst[3] = f2bf(v.w);
      continue;
    }
    i -= 1048576;
    if (i < 65536)  { int n = i >> 7, k = i & 127; tW0T[i] = f2bf(tW0[k * 512 + n]); continue; }
    i -= 65536;
    if (i < 262144) { int n = i >> 9, k = i & 511; tW1T[i] = f2bf(tW1[k * 512 + n]); continue; }
    i -= 262144;
    if (i < 262144) { int n = i >> 9, k = i & 511; aW0T[i] = f2bf(aW0[k * 512 + n]); continue; }
    i -= 262144;
    if (i < 262144) { int n = i >> 9, k = i & 511; vW0T[i] = f2bf(vW0[k * 512 + n]); continue; }
    i -= 262144;
    if (i < 9216)   { int n = i >> 9, k = i & 511; aW1T[i] = f2bf(aW1[k * 18 + n]); continue; }
    i -= 9216;
    if (i < 512)    { vW1T[i] = f2bf(vW1[i]); continue; }
    i -= 512;
    if (i < 1048576){ int g = i >> 9, k = i & 511; WihB[i] = f2bf(Wih[g * 531 + k]); continue; }
    i -= 1048576;
    if (i < 1048576){ WhhB[i] = f2bf(WhhF[i]); continue; }
    i -= 1048576;
    if (i < 2048)   { bsum[i] = bih[i] + bhh[i]; wrc[i] = Wih[i * 531 + 512]; continue; }
    i -= 2048;
    if (i < 36864)  { int j = i >> 11, g = i & 2047; wemb[i] = Wih[g * 531 + 513 + j]; continue; }
    i -= 36864;
    if (i < 1024)   { bcat[i] = (i < 512) ? ab0[i] : vb0[i - 512]; continue; }
    i -= 1024;
    { int b = i >> 9; hring[i] = f2bf(h0[i] * (1.f - done[b])); }  // h_all[0] = h0*keep0
  }
}

// ---------------- bf16 MFMA GEMM: C[M][N] = A[M][K] * Bt[N][K]^T + epilogue ----------------
// Staging via global_load_lds w=16: linear LDS dest, inverse-swizzled global src (rule #21).
template<int MODE>
__global__ __launch_bounds__(256) void gemm_bt(
    const u16* __restrict__ A, const u16* __restrict__ Bt, u16* __restrict__ C,
    int Mdim, int Ndim, int Kdim,
    const float* __restrict__ bias,
    const float* __restrict__ wrc, const float* __restrict__ wemb,
    const float* __restrict__ rin, const int* __restrict__ ain)
{
  __shared__ __align__(16) char smem[32768];  // A tile 16KB | B tile 16KB
  const int tid = threadIdx.x;
  const int nTn = Ndim >> 7;
  int wg = blockIdx.x;
  {  // XCD-aware swizzle (grid % 8 == 0 for all our launches)
    const int per = gridDim.x >> 3;
    wg = (wg & 7) * per + (wg >> 3);
  }
  const int tm = wg / nTn, tn = wg % nTn;
  const int wid = tid >> 6, lane = tid & 63;
  const int wr = wid >> 1, wc = wid & 1;
  const int l15 = lane & 15, l4 = lane >> 4;

  f32x4 acc[4][4];
#pragma unroll
  for (int i = 0; i < 4; ++i)
#pragma unroll
    for (int j = 0; j < 4; ++j) acc[i][j] = f32x4{0.f, 0.f, 0.f, 0.f};

  const int srow = lane >> 3;               // row within 8-row stripe == row&7
  const int scolb = ((lane & 7) * 16) ^ (srow << 4);  // inverse-swizzled byte col
  const size_t kd2 = (size_t)Kdim * 2;
  const char* Abase = (const char*)(A + (size_t)tm * 128 * Kdim);
  const char* Bbase = (const char*)(Bt + (size_t)tn * 128 * Kdim);
  const char* ga[4]; const char* gb[4]; char* la[4]; char* lb[4];
#pragma unroll
  for (int j = 0; j < 4; ++j) {
    const int row = wid * 32 + j * 8 + srow;
    ga[j] = Abase + (size_t)row * kd2 + scolb;
    gb[j] = Bbase + (size_t)row * kd2 + scolb;
    la[j] = smem + wid * 4096 + j * 1024;
    lb[j] = smem + 16384 + wid * 4096 + j * 1024;
  }

  for (int k0 = 0; k0 < Kdim; k0 += 64) {
    const size_t kb = (size_t)k0 * 2;
#pragma unroll
    for (int j = 0; j < 4; ++j) {
      gload16(ga[j] + kb, la[j]);
      gload16(gb[j] + kb, lb[j]);
    }
    __syncthreads();  // drains vmcnt -> LDS tiles complete
#pragma unroll
    for (int kk = 0; kk < 2; ++kk) {
      s16x8 af[4], bfr[4];
#pragma unroll
      for (int i = 0; i < 4; ++i) {
        int ar = wr * 64 + i * 16 + l15;
        af[i] = *(const s16x8*)(smem + ((ar * 128 + kk * 64 + l4 * 16) ^ ((ar & 7) << 4)));
        int br = wc * 64 + i * 16 + l15;
        bfr[i] = *(const s16x8*)(smem + 16384 + ((br * 128 + kk * 64 + l4 * 16) ^ ((br & 7) << 4)));
      }
#pragma unroll
      for (int i = 0; i < 4; ++i)
#pragma unroll
        for (int j = 0; j < 4; ++j)
          acc[i][j] = mfma16x16x32(af[i], bfr[j], acc[i][j]);
    }
    __syncthreads();
  }

#pragma unroll
  for (int i = 0; i < 4; ++i)
#pragma unroll
    for (int j = 0; j < 4; ++j) fence_mfma_read(acc[i][j]);

#pragma unroll
  for (int i = 0; i < 4; ++i) {
    const int rowb = tm * 128 + wr * 64 + i * 16 + l4 * 4;
    float rv[4]; int av[4];
    if (MODE == 1) {
#pragma unroll
      for (int r = 0; r < 4; ++r) { rv[r] = rin[rowb + r]; av[r] = ain[rowb + r]; }
    }
#pragma unroll
    for (int j = 0; j < 4; ++j) {
      const int col = tn * 128 + wc * 64 + j * 16 + l15;
      const float bs = bias[col];
      if (MODE == 0) {
#pragma unroll
        for (int r = 0; r < 4; ++r) {
          float x = acc[i][j][r] + bs;
          x = fmaxf(x, 0.f);
          C[(size_t)(rowb + r) * Ndim + col] = f2bf(x);
        }
      } else {
        const float wcv = wrc[col];
#pragma unroll
        for (int r = 0; r < 4; ++r) {
          float x = acc[i][j][r] + bs + rv[r] * wcv + wemb[av[r] * GGD + col];
          C[(size_t)(rowb + r) * Ndim + col] = f2bf(x);
        }
      }
    }
  }
}

// ---------------- persistent LSTM scan (R4 structure, FIXED barrier) ----------------
// 128 blocks = 4 batch-groups x 32 unit-groups. W_hh slice in LDS once; c in regs;
// h via 2-deep global ring. Barrier fix vs R4: fences are SINGLE-THREAD cache-ops
// (they act cache-wide), polls are RELAXED (no per-iteration invalidate).
// hs stores + xg prefetch + done(t+2) loads overlap the poll window.
__global__ __launch_bounds__(256) void lstm_seq(
    const u16* __restrict__ xg, const u16* __restrict__ WhhB,
    const float* __restrict__ done, const float* __restrict__ c0,
    u16* __restrict__ hring, u16* __restrict__ hs,
    float* __restrict__ hT, float* __restrict__ cT, u32* __restrict__ flags)
{
  __shared__ __align__(16) char wsm[65536];
  const int tid = threadIdx.x;
  const int bg = blockIdx.x & 3;
  const int ug = blockIdx.x >> 2;
  const int b0 = bg * 64;
  const int u0 = ug * 16;

#pragma unroll
  for (int i = 0; i < 16; ++i) {  // stage W_hh slice once: local row lr = gate*16+uu
    int idx = i * 256 + tid;
    int lr = idx >> 6, c8 = idx & 63;
    int g = lr >> 4, uu = lr & 15;
    uint4 v = *(const uint4*)(WhhB + (size_t)(g * 512 + u0 + uu) * 512 + c8 * 8);
    *(uint4*)(wsm + ((lr * 1024 + c8 * 16) ^ ((lr & 7) << 4))) = v;
  }
  __syncthreads();

  const int wid = tid >> 6, lane = tid & 63;
  const int l15 = lane & 15, l4 = lane >> 4;
  const int mrow = wid * 16 + l4 * 4;      // local C/D row base
  const int afrow = b0 + wid * 16 + l15;   // global batch row for A-frag
  const int u = u0 + l15;

  float creg[4], kc[4], kn[4];
#pragma unroll
  for (int r = 0; r < 4; ++r) {
    creg[r] = c0[(size_t)(b0 + mrow + r) * HHD + u];
    kc[r] = 1.f - done[b0 + mrow + r];          // keep(0)
    kn[r] = 1.f - done[BB + b0 + mrow + r];     // keep(1)
  }

  u16 xpf[16];
#pragma unroll
  for (int g = 0; g < 4; ++g)
#pragma unroll
    for (int r = 0; r < 4; ++r)
      xpf[g * 4 + r] = xg[(size_t)(b0 + mrow + r) * GGD + g * HHD + u];

  for (int t = 0; t < TT; ++t) {
    const u16* hsrc = hring + (size_t)(t & 1) * (BB * HHD);
    u16* hdst = hring + (size_t)((t + 1) & 1) * (BB * HHD);

    f32x4 acc[4];
#pragma unroll
    for (int g = 0; g < 4; ++g)
#pragma unroll
      for (int r = 0; r < 4; ++r)
        acc[g][r] = bf2f(xpf[g * 4 + r]);
#pragma unroll
    for (int g = 0; g < 4; ++g) fence_mfma_srcc(acc[g]);  // VALU-write -> MFMA SrcC hazard

    uint4 afr[16];
#pragma unroll
    for (int kk = 0; kk < 16; ++kk)
      afr[kk] = *(const uint4*)(hsrc + (size_t)afrow * HHD + kk * 32 + l4 * 8);
#pragma unroll
    for (int kk = 0; kk < 16; ++kk) {
      s16x8 a = __builtin_bit_cast(s16x8, afr[kk]);
#pragma unroll
      for (int g = 0; g < 4; ++g) {
        int br = g * 16 + l15;
        s16x8 b = *(const s16x8*)(wsm + ((br * 1024 + kk * 64 + l4 * 16) ^ ((br & 7) << 4)));
        acc[g] = mfma16x16x32(a, b, acc[g]);
      }
    }
#pragma unroll
    for (int g = 0; g < 4; ++g) fence_mfma_read(acc[g]);  // drain XDL before VALU reads

    float hv_[4], cv_[4];
#pragma unroll
    for (int r = 0; r < 4; ++r) {
      float iv = sigm(acc[0][r]);
      float fv = sigm(acc[1][r]);
      float gv = tanh_fast(acc[2][r]);
      float ov = sigm(acc[3][r]);
      float c = fv * (creg[r] * kc[r]) + iv * gv;
      float h = ov * tanh_fast(c);
      creg[r] = c; cv_[r] = c; hv_[r] = h;
    }

    if (t < TT - 1) {
      // publish h(t+1) FIRST (critical path), pre-scaled by keep(t+1)
#pragma unroll
      for (int r = 0; r < 4; ++r)
        hdst[(size_t)(b0 + mrow + r) * HHD + u] = f2bf(hv_[r] * kn[r]);
      __syncthreads();  // every wave drains vmcnt -> all block hring stores in L2
      if (tid == 0) {
        __threadfence();  // release (cache-op is XCD-wide; one thread suffices)
        __hip_atomic_store(&flags[(bg * TT + t) * 32 + ug], 1u,
                           __ATOMIC_RELAXED, __HIP_MEMORY_SCOPE_AGENT);
      }
      // ---- overlapped with the poll window: hs stores, xg prefetch, keep rotate ----
#pragma unroll
      for (int r = 0; r < 4; ++r)
        hs[((size_t)t * BB + b0 + mrow + r) * HHD + u] = f2bf(hv_[r]);
#pragma unroll
      for (int g = 0; g < 4; ++g)
#pragma unroll
        for (int r = 0; r < 4; ++r)
          xpf[g * 4 + r] = xg[((size_t)(t + 1) * BB + b0 + mrow + r) * GGD + g * HHD + u];
#pragma unroll
      for (int r = 0; r < 4; ++r) {
        kc[r] = kn[r];
        kn[r] = (t + 2 < TT) ? (1.f - done[(size_t)(t + 2) * BB + b0 + mrow + r]) : 1.f;
      }
      if (tid < 32) {  // RELAXED poll: no cache maintenance per iteration
        while (__hip_atomic_load(&flags[(bg * TT + t) * 32 + tid],
                                 __ATOMIC_RELAXED, __HIP_MEMORY_SCOPE_AGENT) == 0u)
          __builtin_amdgcn_s_sleep(2);
      }
      __syncthreads();
      if (tid == 0) __threadfence();  // acquire: invalidate stale hring lines
      __syncthreads();
    } else {
#pragma unroll
      for (int r = 0; r < 4; ++r) {
        hs[((size_t)t * BB + b0 + mrow + r) * HHD + u] = f2bf(hv_[r]);
        hT[(size_t)(b0 + mrow + r) * HHD + u] = hv_[r];
        cT[(size_t)(b0 + mrow + r) * HHD + u] = cv_[r];
      }
    }
  }
}

// ---------------- final heads: adv(18) + val + dueling combine ----------------
__global__ __launch_bounds__(256) void head_final(
    const u16* __restrict__ hv, const u16* __restrict__ aW1T,
    const u16* __restrict__ vW1T, const float* __restrict__ ab1,
    const float* __restrict__ vb1, float* __restrict__ q)
{
  __shared__ __align__(16) u16 wa[AD * HHD];
  __shared__ __align__(16) u16 wv[HHD];
  const int tid = threadIdx.x;
  for (int i = tid; i < AD * HHD / 8; i += 256) ((uint4*)wa)[i] = ((const uint4*)aW1T)[i];
  for (int i = tid; i < HHD / 8; i += 256) ((uint4*)wv)[i] = ((const uint4*)vW1T)[i];
  __syncthreads();
  const int wid = tid >> 6, lane = tid & 63;
  for (int row = blockIdx.x * 4 + wid; row < MMD; row += gridDim.x * 4) {
    uint4 va = *(const uint4*)(hv + (size_t)row * 1024 + lane * 8);
    uint4 vv = *(const uint4*)(hv + (size_t)row * 1024 + 512 + lane * 8);
    const u16* pa = (const u16*)&va;
    const u16* pv = (const u16*)&vv;
    float af[8], vf[8];
#pragma unroll
    for (int j = 0; j < 8; ++j) { af[j] = bf2f(pa[j]); vf[j] = bf2f(pv[j]); }
    float accs[19];
#pragma unroll
    for (int n = 0; n < 19; ++n) accs[n] = 0.f;
#pragma unroll
    for (int n = 0; n < AD; ++n) {
      const u16* w = wa + n * HHD + lane * 8;
#pragma unroll
      for (int j = 0; j < 8; ++j) accs[n] += af[j] * bf2f(w[j]);
    }
    {
      const u16* w = wv + lane * 8;
#pragma unroll
      for (int j = 0; j < 8; ++j) accs[18] += vf[j] * bf2f(w[j]);
    }
#pragma unroll
    for (int n = 0; n < 19; ++n) {
#pragma unroll
      for (int off = 32; off > 0; off >>= 1)
        accs[n] += __shfl_xor(accs[n], off, 64);
    }
    if (lane == 0) {
      float s = 0.f;
      float advv[AD];
#pragma unroll
      for (int n = 0; n < AD; ++n) { advv[n] = accs[n] + ab1[n]; s += advv[n]; }
      float val = accs[18] + vb1[0];
      float mean = s * (1.f / 18.f);
#pragma unroll
      for (int n = 0; n < AD; ++n) q[(size_t)row * AD + n] = val + advv[n] - mean;
    }
  }
}

// ---------------- launch ----------------
extern "C" void kernel_launch(void* const* d_in, const int* in_sizes, int n_in,
                              void* d_out, int out_size, void* d_ws, size_t ws_size,
                              hipStream_t stream) {
  const float* o    = (const float*)d_in[0];
  const int*   a    = (const int*)d_in[1];
  const float* r    = (const float*)d_in[2];
  const float* done = (const float*)d_in[3];
  const float* h0   = (const float*)d_in[4];
  const float* c0   = (const float*)d_in[5];
  const float* tW0  = (const float*)d_in[6];
  const float* tb0  = (const float*)d_in[7];
  const float* tW1  = (const float*)d_in[8];
  const float* tb1  = (const float*)d_in[9];
  const float* Wih  = (const float*)d_in[10];
  const float* Whh  = (const float*)d_in[11];
  const float* bih  = (const float*)d_in[12];
  const float* bhh  = (const float*)d_in[13];
  const float* aW0  = (const float*)d_in[14];
  const float* ab0  = (const float*)d_in[15];
  const float* aW1  = (const float*)d_in[16];
  const float* ab1  = (const float*)d_in[17];
  const float* vW0  = (const float*)d_in[18];
  const float* vb0  = (const float*)d_in[19];
  const float* vW1  = (const float*)d_in[20];
  const float* vb1  = (const float*)d_in[21];
  (void)in_sizes; (void)n_in; (void)ws_size;

  char* ws = (char*)d_ws;
  u32* flags  = (u32*)(ws + OFF_FLAGS);
  u16* hring  = (u16*)(ws + OFF_HRING);
  u16* tW0T   = (u16*)(ws + OFF_TW0T);
  u16* tW1T   = (u16*)(ws + OFF_TW1T);
  u16* aW0T   = (u16*)(ws + OFF_AW0T);  // aW0T||vW0T contiguous => [1024][512]
  u16* vW0T   = (u16*)(ws + OFF_VW0T);
  u16* aW1T   = (u16*)(ws + OFF_AW1T);
  u16* vW1T   = (u16*)(ws + OFF_VW1T);
  u16* WihB   = (u16*)(ws + OFF_WIH);
  u16* WhhB   = (u16*)(ws + OFF_WHH);
  float* bsum = (float*)(ws + OFF_BSUM);
  float* wrc  = (float*)(ws + OFF_WRC);
  float* wemb = (float*)(ws + OFF_WEMB);
  float* bcat = (float*)(ws + OFF_BCAT);
  u16* o_bf   = (u16*)(ws + OFF_OBF);
  u16* buf1   = (u16*)(ws + OFF_BUF1);  // h1, later hs
  u16* buf2   = (u16*)(ws + OFF_BUF2);  // hid
  u16* buf3   = (u16*)(ws + OFF_BUF3);  // xg, later hv

  float* qout = (float*)d_out;
  float* hT   = qout + (size_t)TT * BB * AD;
  float* cT   = hT + (size_t)BB * HHD;

  hipMemsetAsync(flags, 0, 65536, stream);
  prep<<<2048, 256, 0, stream>>>(o, tW0, tW1, aW0, vW0, aW1, vW1, Wih, Whh,
                                 bih, bhh, h0, done, ab0, vb0,
                                 o_bf, tW0T, tW1T, aW0T, vW0T, aW1T, vW1T,
                                 WihB, WhhB, bsum, wrc, wemb, bcat, hring);
  gemm_bt<0><<<1024, 256, 0, stream>>>(o_bf, tW0T, buf1, MMD, 512, 128, tb0,
                                       nullptr, nullptr, nullptr, nullptr);
  gemm_bt<0><<<1024, 256, 0, stream>>>(buf1, tW1T, buf2, MMD, 512, 512, tb1,
                                       nullptr, nullptr, nullptr, nullptr);
  gemm_bt<1><<<4096, 256, 0, stream>>>(buf2, WihB, buf3, MMD, 2048, 512, bsum,
                                       wrc, wemb, r, a);
  lstm_seq<<<128, 256, 0, stream>>>(buf3, WhhB, done, c0, hring,
                                    buf1 /*hs*/, hT, cT, flags);
  gemm_bt<0><<<2048, 256, 0, stream>>>(buf1 /*hs*/, aW0T, buf3 /*hv*/, MMD, 1024, 512, bcat,
                                       nullptr, nullptr, nullptr, nullptr);
  head_final<<<2048, 256, 0, stream>>>(buf3, aW1T, vW1T, ab1, vb1, qout);
}

// Round 8
// 1112.419 us; speedup vs baseline: 9.4793x; 1.5215x over previous
//
#include <hip/hip_runtime.h>
#include <cstdint>

typedef unsigned short u16;
typedef unsigned int u32;
typedef unsigned long long u64;
typedef float f32x4 __attribute__((ext_vector_type(4)));
typedef short s16x8 __attribute__((ext_vector_type(8)));

#define DEV static __device__ __forceinline__

#define TT 128
#define BB 256
#define OBSD 128
#define HHD 512
#define AD 18
#define GGD 2048
#define MMD 32768

DEV u16 f2bf(float f) {
  u32 u = __builtin_bit_cast(u32, f);
  u += 0x7fffu + ((u >> 16) & 1u);
  return (u16)(u >> 16);
}
DEV float bf2f(u16 h) { return __builtin_bit_cast(float, ((u32)h) << 16); }

DEV f32x4 mfma16x16x32(s16x8 a, s16x8 b, f32x4 c) {
  // D = A*B + C, C/D layout: col=lane&15, row=(lane>>4)*4+reg  [m89/m91]
  asm("v_mfma_f32_16x16x32_bf16 %0, %1, %2, %0" : "+v"(c) : "v"(a), "v"(b));
  return c;
}
// Inline-asm MFMA: hazard recognizer can't see it -> manual wait states (proven R3).
DEV void fence_mfma_read(f32x4& x) { asm volatile("s_nop 7" : "+v"(x)); }
DEV void fence_mfma_srcc(f32x4& x) { asm volatile("s_nop 1" : "+v"(x)); }

// async global->LDS, 16B/lane; LDS dest is wave-uniform base + lane*16 (m97/m104)
typedef __attribute__((address_space(3))) char lds_char;
typedef __attribute__((address_space(1))) const char gl_char;
DEV void gload16(const char* g, char* l) {
  __builtin_amdgcn_global_load_lds((const gl_char*)g, (lds_char*)l, 16, 0, 0);
}

DEV float sigm(float x) { return 1.f / (1.f + __expf(-x)); }
DEV float tanh_fast(float x) {
  float t = __expf(-2.f * fabsf(x));
  float r = (1.f - t) / (1.f + t);
  return copysignf(r, x);
}

// ---------------- workspace layout (bytes), total ~218MB ----------------
constexpr size_t OFF_FLAGS = 0;          // 65536 (4bg x 128t x 32ug x 4B)
constexpr size_t OFF_HRING = 524288;     // 524288  (2 x [256][512] bf16)
constexpr size_t OFF_TW0T  = 1048576;    // 131072
constexpr size_t OFF_TW1T  = 1179648;    // 524288
constexpr size_t OFF_AW0T  = 1703936;    // 524288
constexpr size_t OFF_VW0T  = 2228224;    // 524288 (contiguous with AW0T)
constexpr size_t OFF_AW1T  = 2752512;    // 18432
constexpr size_t OFF_VW1T  = 2770944;    // 1024
constexpr size_t OFF_WIH   = 2772992;    // 2097152
constexpr size_t OFF_WHH   = 4870144;    // 2097152
constexpr size_t OFF_BSUM  = 6967296;    // 8192
constexpr size_t OFF_WRC   = 6975488;    // 8192
constexpr size_t OFF_WEMB  = 6983680;    // 147456
constexpr size_t OFF_BCAT  = 7131136;    // 4096
constexpr size_t OFF_OBF   = 8388608;    // 8388608
constexpr size_t OFF_BUF1  = 16777216;   // 33554432  (h1, later hs)
constexpr size_t OFF_BUF2  = 50331648;   // 33554432  (hid)
constexpr size_t OFF_BUF3  = 83886080;   // 134217728 (xg, later hv [32768][1024])

// ---------------- prep: convert/transpose weights, convert o, init h-ring ----------------
__global__ __launch_bounds__(256) void prep(
    const float* __restrict__ o, const float* __restrict__ tW0,
    const float* __restrict__ tW1, const float* __restrict__ aW0,
    const float* __restrict__ vW0, const float* __restrict__ aW1,
    const float* __restrict__ vW1, const float* __restrict__ Wih,
    const float* __restrict__ WhhF, const float* __restrict__ bih,
    const float* __restrict__ bhh, const float* __restrict__ h0,
    const float* __restrict__ done, const float* __restrict__ ab0,
    const float* __restrict__ vb0,
    u16* __restrict__ o_bf, u16* __restrict__ tW0T, u16* __restrict__ tW1T,
    u16* __restrict__ aW0T, u16* __restrict__ vW0T, u16* __restrict__ aW1T,
    u16* __restrict__ vW1T, u16* __restrict__ WihB, u16* __restrict__ WhhB,
    float* __restrict__ bsum, float* __restrict__ wrc, float* __restrict__ wemb,
    float* __restrict__ bcat, u16* __restrict__ hring)
{
  const int total = 4178432;
  for (int id = blockIdx.x * 256 + threadIdx.x; id < total; id += gridDim.x * 256) {
    int i = id;
    if (i < 1048576) {  // o -> bf16, x4
      float4 v = ((const float4*)o)[i];
      u16* dst = o_bf + (size_t)i * 4;
      dst[0] = f2bf(v.x); dst[1] = f2bf(v.y); dst[2] = f2bf(v.z); dst[3] = f2bf(v.w);
      continue;
    }
    i -= 1048576;
    if (i < 65536)  { int n = i >> 7, k = i & 127; tW0T[i] = f2bf(tW0[k * 512 + n]); continue; }
    i -= 65536;
    if (i < 262144) { int n = i >> 9, k = i & 511; tW1T[i] = f2bf(tW1[k * 512 + n]); continue; }
    i -= 262144;
    if (i < 262144) { int n = i >> 9, k = i & 511; aW0T[i] = f2bf(aW0[k * 512 + n]); continue; }
    i -= 262144;
    if (i < 262144) { int n = i >> 9, k = i & 511; vW0T[i] = f2bf(vW0[k * 512 + n]); continue; }
    i -= 262144;
    if (i < 9216)   { int n = i >> 9, k = i & 511; aW1T[i] = f2bf(aW1[k * 18 + n]); continue; }
    i -= 9216;
    if (i < 512)    { vW1T[i] = f2bf(vW1[i]); continue; }
    i -= 512;
    if (i < 1048576){ int g = i >> 9, k = i & 511; WihB[i] = f2bf(Wih[g * 531 + k]); continue; }
    i -= 1048576;
    if (i < 1048576){ WhhB[i] = f2bf(WhhF[i]); continue; }
    i -= 1048576;
    if (i < 2048)   { bsum[i] = bih[i] + bhh[i]; wrc[i] = Wih[i * 531 + 512]; continue; }
    i -= 2048;
    if (i < 36864)  { int j = i >> 11, g = i & 2047; wemb[i] = Wih[g * 531 + 513 + j]; continue; }
    i -= 36864;
    if (i < 1024)   { bcat[i] = (i < 512) ? ab0[i] : vb0[i - 512]; continue; }
    i -= 1024;
    { int b = i >> 9; hring[i] = f2bf(h0[i] * (1.f - done[b])); }  // h_all[0] = h0*keep0
  }
}

// ---------------- bf16 MFMA GEMM: C[M][N] = A[M][K] * Bt[N][K]^T + epilogue ----------------
// Staging via global_load_lds w=16: linear LDS dest, inverse-swizzled global src (rule #21).
template<int MODE>
__global__ __launch_bounds__(256) void gemm_bt(
    const u16* __restrict__ A, const u16* __restrict__ Bt, u16* __restrict__ C,
    int Mdim, int Ndim, int Kdim,
    const float* __restrict__ bias,
    const float* __restrict__ wrc, const float* __restrict__ wemb,
    const float* __restrict__ rin, const int* __restrict__ ain)
{
  __shared__ __align__(16) char smem[32768];  // A tile 16KB | B tile 16KB
  const int tid = threadIdx.x;
  const int nTn = Ndim >> 7;
  int wg = blockIdx.x;
  {  // XCD-aware swizzle (grid % 8 == 0 for all our launches)
    const int per = gridDim.x >> 3;
    wg = (wg & 7) * per + (wg >> 3);
  }
  const int tm = wg / nTn, tn = wg % nTn;
  const int wid = tid >> 6, lane = tid & 63;
  const int wr = wid >> 1, wc = wid & 1;
  const int l15 = lane & 15, l4 = lane >> 4;

  f32x4 acc[4][4];
#pragma unroll
  for (int i = 0; i < 4; ++i)
#pragma unroll
    for (int j = 0; j < 4; ++j) acc[i][j] = f32x4{0.f, 0.f, 0.f, 0.f};

  const int srow = lane >> 3;               // row within 8-row stripe == row&7
  const int scolb = ((lane & 7) * 16) ^ (srow << 4);  // inverse-swizzled byte col
  const size_t kd2 = (size_t)Kdim * 2;
  const char* Abase = (const char*)(A + (size_t)tm * 128 * Kdim);
  const char* Bbase = (const char*)(Bt + (size_t)tn * 128 * Kdim);
  const char* ga[4]; const char* gb[4]; char* la[4]; char* lb[4];
#pragma unroll
  for (int j = 0; j < 4; ++j) {
    const int row = wid * 32 + j * 8 + srow;
    ga[j] = Abase + (size_t)row * kd2 + scolb;
    gb[j] = Bbase + (size_t)row * kd2 + scolb;
    la[j] = smem + wid * 4096 + j * 1024;
    lb[j] = smem + 16384 + wid * 4096 + j * 1024;
  }

  for (int k0 = 0; k0 < Kdim; k0 += 64) {
    const size_t kb = (size_t)k0 * 2;
#pragma unroll
    for (int j = 0; j < 4; ++j) {
      gload16(ga[j] + kb, la[j]);
      gload16(gb[j] + kb, lb[j]);
    }
    __syncthreads();  // drains vmcnt -> LDS tiles complete
#pragma unroll
    for (int kk = 0; kk < 2; ++kk) {
      s16x8 af[4], bfr[4];
#pragma unroll
      for (int i = 0; i < 4; ++i) {
        int ar = wr * 64 + i * 16 + l15;
        af[i] = *(const s16x8*)(smem + ((ar * 128 + kk * 64 + l4 * 16) ^ ((ar & 7) << 4)));
        int br = wc * 64 + i * 16 + l15;
        bfr[i] = *(const s16x8*)(smem + 16384 + ((br * 128 + kk * 64 + l4 * 16) ^ ((br & 7) << 4)));
      }
#pragma unroll
      for (int i = 0; i < 4; ++i)
#pragma unroll
        for (int j = 0; j < 4; ++j)
          acc[i][j] = mfma16x16x32(af[i], bfr[j], acc[i][j]);
    }
    __syncthreads();
  }

#pragma unroll
  for (int i = 0; i < 4; ++i)
#pragma unroll
    for (int j = 0; j < 4; ++j) fence_mfma_read(acc[i][j]);

#pragma unroll
  for (int i = 0; i < 4; ++i) {
    const int rowb = tm * 128 + wr * 64 + i * 16 + l4 * 4;
    float rv[4]; int av[4];
    if (MODE == 1) {
#pragma unroll
      for (int r = 0; r < 4; ++r) { rv[r] = rin[rowb + r]; av[r] = ain[rowb + r]; }
    }
#pragma unroll
    for (int j = 0; j < 4; ++j) {
      const int col = tn * 128 + wc * 64 + j * 16 + l15;
      const float bs = bias[col];
      if (MODE == 0) {
#pragma unroll
        for (int r = 0; r < 4; ++r) {
          float x = acc[i][j][r] + bs;
          x = fmaxf(x, 0.f);
          C[(size_t)(rowb + r) * Ndim + col] = f2bf(x);
        }
      } else {
        const float wcv = wrc[col];
#pragma unroll
        for (int r = 0; r < 4; ++r) {
          float x = acc[i][j][r] + bs + rv[r] * wcv + wemb[av[r] * GGD + col];
          C[(size_t)(rowb + r) * Ndim + col] = f2bf(x);
        }
      }
    }
  }
}

// ---------------- persistent LSTM scan (R7 structure, FENCE-FREE barrier) ----------------
// All hring traffic is relaxed agent-scope atomic (sc1: bypasses non-coherent L1/L2,
// coherent at LLC) -> NO buffer_wbl2/buffer_inv cache walks per step. Release =
// __syncthreads (vmcnt(0) drains sc1 stores to LLC) + relaxed flag store; acquire =
// nothing (sc1 loads read LLC directly). Flag/poll structure proven in R7.
__global__ __launch_bounds__(256) void lstm_seq(
    const u16* __restrict__ xg, const u16* __restrict__ WhhB,
    const float* __restrict__ done, const float* __restrict__ c0,
    u16* __restrict__ hring, u16* __restrict__ hs,
    float* __restrict__ hT, float* __restrict__ cT, u32* __restrict__ flags)
{
  __shared__ __align__(16) char wsm[65536];
  const int tid = threadIdx.x;
  const int bg = blockIdx.x & 3;
  const int ug = blockIdx.x >> 2;
  const int b0 = bg * 64;
  const int u0 = ug * 16;

#pragma unroll
  for (int i = 0; i < 16; ++i) {  // stage W_hh slice once: local row lr = gate*16+uu
    int idx = i * 256 + tid;
    int lr = idx >> 6, c8 = idx & 63;
    int g = lr >> 4, uu = lr & 15;
    uint4 v = *(const uint4*)(WhhB + (size_t)(g * 512 + u0 + uu) * 512 + c8 * 8);
    *(uint4*)(wsm + ((lr * 1024 + c8 * 16) ^ ((lr & 7) << 4))) = v;
  }
  __syncthreads();

  const int wid = tid >> 6, lane = tid & 63;
  const int l15 = lane & 15, l4 = lane >> 4;
  const int mrow = wid * 16 + l4 * 4;      // local C/D row base
  const int afrow = b0 + wid * 16 + l15;   // global batch row for A-frag
  const int u = u0 + l15;

  float creg[4], kc[4], kn[4];
#pragma unroll
  for (int r = 0; r < 4; ++r) {
    creg[r] = c0[(size_t)(b0 + mrow + r) * HHD + u];
    kc[r] = 1.f - done[b0 + mrow + r];          // keep(0)
    kn[r] = 1.f - done[BB + b0 + mrow + r];     // keep(1)
  }

  u16 xpf[16];
#pragma unroll
  for (int g = 0; g < 4; ++g)
#pragma unroll
    for (int r = 0; r < 4; ++r)
      xpf[g * 4 + r] = xg[(size_t)(b0 + mrow + r) * GGD + g * HHD + u];

  for (int t = 0; t < TT; ++t) {
    const u16* hsrc = hring + (size_t)(t & 1) * (BB * HHD);
    u16* hdst = hring + (size_t)((t + 1) & 1) * (BB * HHD);

    f32x4 acc[4];
#pragma unroll
    for (int g = 0; g < 4; ++g)
#pragma unroll
      for (int r = 0; r < 4; ++r)
        acc[g][r] = bf2f(xpf[g * 4 + r]);
#pragma unroll
    for (int g = 0; g < 4; ++g) fence_mfma_srcc(acc[g]);  // VALU-write -> MFMA SrcC hazard

    // A-frags: device-coherent u64 loads from LLC (compiler-tracked vmcnt)
    u64 aflo[16], afhi[16];
    const u64* hb = (const u64*)(hsrc + (size_t)afrow * HHD);
#pragma unroll
    for (int kk = 0; kk < 16; ++kk) {
      aflo[kk] = __hip_atomic_load(hb + kk * 8 + l4 * 2,
                                   __ATOMIC_RELAXED, __HIP_MEMORY_SCOPE_AGENT);
      afhi[kk] = __hip_atomic_load(hb + kk * 8 + l4 * 2 + 1,
                                   __ATOMIC_RELAXED, __HIP_MEMORY_SCOPE_AGENT);
    }
#pragma unroll
    for (int kk = 0; kk < 16; ++kk) {
      union { u64 q[2]; s16x8 v; } tmp;
      tmp.q[0] = aflo[kk]; tmp.q[1] = afhi[kk];
      s16x8 a = tmp.v;
#pragma unroll
      for (int g = 0; g < 4; ++g) {
        int br = g * 16 + l15;
        s16x8 b = *(const s16x8*)(wsm + ((br * 1024 + kk * 64 + l4 * 16) ^ ((br & 7) << 4)));
        acc[g] = mfma16x16x32(a, b, acc[g]);
      }
    }
#pragma unroll
    for (int g = 0; g < 4; ++g) fence_mfma_read(acc[g]);  // drain XDL before VALU reads

    float hv_[4], cv_[4];
#pragma unroll
    for (int r = 0; r < 4; ++r) {
      float iv = sigm(acc[0][r]);
      float fv = sigm(acc[1][r]);
      float gv = tanh_fast(acc[2][r]);
      float ov = sigm(acc[3][r]);
      float c = fv * (creg[r] * kc[r]) + iv * gv;
      float h = ov * tanh_fast(c);
      creg[r] = c; cv_[r] = c; hv_[r] = h;
    }

    if (t < TT - 1) {
      // publish h(t+1), pre-scaled by keep(t+1): paired-lane packed u32 sc1 stores
      u32 pw[4];
#pragma unroll
      for (int r = 0; r < 4; ++r) {
        u16 ob = f2bf(hv_[r] * kn[r]);
        u16 pb = (u16)__shfl_xor((int)ob, 1, 64);
        pw[r] = ((l15 & 1) == 0) ? ((u32)ob | ((u32)pb << 16))
                                 : ((u32)pb | ((u32)ob << 16));
      }
      {
        const int rb = (l15 & 1) * 2;
        u32* hd32 = (u32*)hdst;
        const int col2 = (u0 + (l15 & ~1)) >> 1;
        __hip_atomic_store(&hd32[(size_t)(b0 + mrow + rb) * 256 + col2], pw[rb],
                           __ATOMIC_RELAXED, __HIP_MEMORY_SCOPE_AGENT);
        __hip_atomic_store(&hd32[(size_t)(b0 + mrow + rb + 1) * 256 + col2], pw[rb + 1],
                           __ATOMIC_RELAXED, __HIP_MEMORY_SCOPE_AGENT);
      }
      __syncthreads();  // every wave: s_waitcnt vmcnt(0) -> sc1 stores acked at LLC
      if (tid == 0)
        __hip_atomic_store(&flags[(bg * TT + t) * 32 + ug], 1u,
                           __ATOMIC_RELAXED, __HIP_MEMORY_SCOPE_AGENT);
      // ---- overlapped with poll window: hs stores, xg prefetch, keep rotate ----
#pragma unroll
      for (int r = 0; r < 4; ++r)
        hs[((size_t)t * BB + b0 + mrow + r) * HHD + u] = f2bf(hv_[r]);
#pragma unroll
      for (int g = 0; g < 4; ++g)
#pragma unroll
        for (int r = 0; r < 4; ++r)
          xpf[g * 4 + r] = xg[((size_t)(t + 1) * BB + b0 + mrow + r) * GGD + g * HHD + u];
#pragma unroll
      for (int r = 0; r < 4; ++r) {
        kc[r] = kn[r];
        kn[r] = (t + 2 < TT) ? (1.f - done[(size_t)(t + 2) * BB + b0 + mrow + r]) : 1.f;
      }
      if (tid < 32) {  // relaxed sc1 poll: no cache maintenance
        while (__hip_atomic_load(&flags[(bg * TT + t) * 32 + tid],
                                 __ATOMIC_RELAXED, __HIP_MEMORY_SCOPE_AGENT) == 0u)
          __builtin_amdgcn_s_sleep(1);
      }
      __syncthreads();  // no acquire fence needed: next A-frags are sc1 loads
    } else {
#pragma unroll
      for (int r = 0; r < 4; ++r) {
        hs[((size_t)t * BB + b0 + mrow + r) * HHD + u] = f2bf(hv_[r]);
        hT[(size_t)(b0 + mrow + r) * HHD + u] = hv_[r];
        cT[(size_t)(b0 + mrow + r) * HHD + u] = cv_[r];
      }
    }
  }
}

// ---------------- final heads: adv(18) + val + dueling combine ----------------
__global__ __launch_bounds__(256) void head_final(
    const u16* __restrict__ hv, const u16* __restrict__ aW1T,
    const u16* __restrict__ vW1T, const float* __restrict__ ab1,
    const float* __restrict__ vb1, float* __restrict__ q)
{
  __shared__ __align__(16) u16 wa[AD * HHD];
  __shared__ __align__(16) u16 wv[HHD];
  const int tid = threadIdx.x;
  for (int i = tid; i < AD * HHD / 8; i += 256) ((uint4*)wa)[i] = ((const uint4*)aW1T)[i];
  for (int i = tid; i < HHD / 8; i += 256) ((uint4*)wv)[i] = ((const uint4*)vW1T)[i];
  __syncthreads();
  const int wid = tid >> 6, lane = tid & 63;
  for (int row = blockIdx.x * 4 + wid; row < MMD; row += gridDim.x * 4) {
    uint4 va = *(const uint4*)(hv + (size_t)row * 1024 + lane * 8);
    uint4 vv = *(const uint4*)(hv + (size_t)row * 1024 + 512 + lane * 8);
    const u16* pa = (const u16*)&va;
    const u16* pv = (const u16*)&vv;
    float af[8], vf[8];
#pragma unroll
    for (int j = 0; j < 8; ++j) { af[j] = bf2f(pa[j]); vf[j] = bf2f(pv[j]); }
    float accs[19];
#pragma unroll
    for (int n = 0; n < 19; ++n) accs[n] = 0.f;
#pragma unroll
    for (int n = 0; n < AD; ++n) {
      const u16* w = wa + n * HHD + lane * 8;
#pragma unroll
      for (int j = 0; j < 8; ++j) accs[n] += af[j] * bf2f(w[j]);
    }
    {
      const u16* w = wv + lane * 8;
#pragma unroll
      for (int j = 0; j < 8; ++j) accs[18] += vf[j] * bf2f(w[j]);
    }
#pragma unroll
    for (int n = 0; n < 19; ++n) {
#pragma unroll
      for (int off = 32; off > 0; off >>= 1)
        accs[n] += __shfl_xor(accs[n], off, 64);
    }
    if (lane == 0) {
      float s = 0.f;
      float advv[AD];
#pragma unroll
      for (int n = 0; n < AD; ++n) { advv[n] = accs[n] + ab1[n]; s += advv[n]; }
      float val = accs[18] + vb1[0];
      float mean = s * (1.f / 18.f);
#pragma unroll
      for (int n = 0; n < AD; ++n) q[(size_t)row * AD + n] = val + advv[n] - mean;
    }
  }
}

// ---------------- launch ----------------
extern "C" void kernel_launch(void* const* d_in, const int* in_sizes, int n_in,
                              void* d_out, int out_size, void* d_ws, size_t ws_size,
                              hipStream_t stream) {
  const float* o    = (const float*)d_in[0];
  const int*   a    = (const int*)d_in[1];
  const float* r    = (const float*)d_in[2];
  const float* done = (const float*)d_in[3];
  const float* h0   = (const float*)d_in[4];
  const float* c0   = (const float*)d_in[5];
  const float* tW0  = (const float*)d_in[6];
  const float* tb0  = (const float*)d_in[7];
  const float* tW1  = (const float*)d_in[8];
  const float* tb1  = (const float*)d_in[9];
  const float* Wih  = (const float*)d_in[10];
  const float* Whh  = (const float*)d_in[11];
  const float* bih  = (const float*)d_in[12];
  const float* bhh  = (const float*)d_in[13];
  const float* aW0  = (const float*)d_in[14];
  const float* ab0  = (const float*)d_in[15];
  const float* aW1  = (const float*)d_in[16];
  const float* ab1  = (const float*)d_in[17];
  const float* vW0  = (const float*)d_in[18];
  const float* vb0  = (const float*)d_in[19];
  const float* vW1  = (const float*)d_in[20];
  const float* vb1  = (const float*)d_in[21];
  (void)in_sizes; (void)n_in; (void)ws_size;

  char* ws = (char*)d_ws;
  u32* flags  = (u32*)(ws + OFF_FLAGS);
  u16* hring  = (u16*)(ws + OFF_HRING);
  u16* tW0T   = (u16*)(ws + OFF_TW0T);
  u16* tW1T   = (u16*)(ws + OFF_TW1T);
  u16* aW0T   = (u16*)(ws + OFF_AW0T);  // aW0T||vW0T contiguous => [1024][512]
  u16* vW0T   = (u16*)(ws + OFF_VW0T);
  u16* aW1T   = (u16*)(ws + OFF_AW1T);
  u16* vW1T   = (u16*)(ws + OFF_VW1T);
  u16* WihB   = (u16*)(ws + OFF_WIH);
  u16* WhhB   = (u16*)(ws + OFF_WHH);
  float* bsum = (float*)(ws + OFF_BSUM);
  float* wrc  = (float*)(ws + OFF_WRC);
  float* wemb = (float*)(ws + OFF_WEMB);
  float* bcat = (float*)(ws + OFF_BCAT);
  u16* o_bf   = (u16*)(ws + OFF_OBF);
  u16* buf1   = (u16*)(ws + OFF_BUF1);  // h1, later hs
  u16* buf2   = (u16*)(ws + OFF_BUF2);  // hid
  u16* buf3   = (u16*)(ws + OFF_BUF3);  // xg, later hv

  float* qout = (float*)d_out;
  float* hT   = qout + (size_t)TT * BB * AD;
  float* cT   = hT + (size_t)BB * HHD;

  hipMemsetAsync(flags, 0, 65536, stream);
  prep<<<2048, 256, 0, stream>>>(o, tW0, tW1, aW0, vW0, aW1, vW1, Wih, Whh,
                                 bih, bhh, h0, done, ab0, vb0,
                                 o_bf, tW0T, tW1T, aW0T, vW0T, aW1T, vW1T,
                                 WihB, WhhB, bsum, wrc, wemb, bcat, hring);
  gemm_bt<0><<<1024, 256, 0, stream>>>(o_bf, tW0T, buf1, MMD, 512, 128, tb0,
                                       nullptr, nullptr, nullptr, nullptr);
  gemm_bt<0><<<1024, 256, 0, stream>>>(buf1, tW1T, buf2, MMD, 512, 512, tb1,
                                       nullptr, nullptr, nullptr, nullptr);
  gemm_bt<1><<<4096, 256, 0, stream>>>(buf2, WihB, buf3, MMD, 2048, 512, bsum,
                                       wrc, wemb, r, a);
  lstm_seq<<<128, 256, 0, stream>>>(buf3, WhhB, done, c0, hring,
                                    buf1 /*hs*/, hT, cT, flags);
  gemm_bt<0><<<2048, 256, 0, stream>>>(buf1 /*hs*/, aW0T, buf3 /*hv*/, MMD, 1024, 512, bcat,
                                       nullptr, nullptr, nullptr, nullptr);
  head_final<<<2048, 256, 0, stream>>>(buf3, aW1T, vW1T, ab1, vb1, qout);
}